// Round 6
// baseline (371.101 us; speedup 1.0000x reference)
//
#include <hip/hip_runtime.h>
#include <math.h>

// LIF spiking-neuron scan: N=65536 rows, T=512 sequential steps/row.
// d_out = [spikes (N*T) | mems (N*T)] fp32.
//
// History:
//  R2/R4/R6  : 362 +- 1.5us total — three structural rewrites, all null.
//  R7 PROBE  : kernel launched twice -> 439.1. KERNEL = 77.5us.
//              dur = ~284us fixed harness poison overhead + kernel.
//              Kernel: 403MB / 77.5us = 5.2 TB/s (82% of 6.3 copy ceiling).
//  R8        : PAD 65->68, all-b128 LDS (240 -> 60 DS instrs/wave/chunk):
//              361.0us = NULL. DS pipe was never the critical path
//              (post-R8 accounting: VALU ~11us, DS ~13us, VMEM issue ~3us,
//              HBM ~64us — HBM dominates; kernel at 77.5).
//
// R9 — last single-variable lever between 5.2 and 6.3 TB/s: the
// NONTEMPORAL hints. NT stores bypass L2; the harness's own fill — the
// fastest writer observed (6.5 TB/s) — writes THROUGH L2, which absorbs
// full lines and streams them back. Our 268MB of NT stores may forfeit
// exactly that. NT was added in R4 bundled with other changes during the
// mis-measurement era; its isolated effect was never tested. R9 = R8 with
// plain loads/stores (through L2). Nothing else changes.
// Predict: if NT hurt -> kernel 77.5 -> ~64-70, dur -> ~348-355.
// If null (361 +- 2) -> kernel is AT the mixed-stream HBM ceiling for a
// 1-read:2-write pattern; declare roofline.
//
// NUMERICS: bit-exact vs numpy verified — no FMA contraction on the
// recurrence (__f*_rn intrinsics only), sigmoid(beta_) double-rounded
// once to fp32. Do not change.
//
// R5 bug (kept fixed): compiler may reorder cross-lane LDS deps it can
// prove per-thread-disjoint; WAVE_FENCE() (zero-cost compiler fence) at
// every phase boundary pins program order; HW DS pipe is in-order.

typedef float f32x4 __attribute__((ext_vector_type(4)));

#define WAVE_FENCE() asm volatile("" ::: "memory")

constexpr int N_BATCH = 65536;
constexpr int T_STEPS = 512;
constexpr int BLOCK   = 64;              // ONE wave — wave-synchronous
constexpr int ROWS    = 16;              // rows per block (compute lanes 0..15)
constexpr int TILE    = 64;              // steps per chunk = 256B per row
constexpr int NCH     = T_STEPS / TILE;  // 8 chunks
constexpr int PAD     = 68;              // floats/row: 272B = 16B-aligned, 68%32=4 -> conflict-free
constexpr int RPF     = T_STEPS / 4;     // 128: global row pitch in float4
constexpr int LPC     = ROWS * TILE / (BLOCK * 4);  // 4 load instrs per chunk

// I/O lane roles: rsub = t>>4 (0..3), a = t&15 (float4 within the 256B
// chunk). Instruction p covers rows p*4+rsub -> 4 rows x 256B = 8 full
// 128B lines per instruction.

__device__ __forceinline__ void prefetch_chunk(f32x4 (&v)[LPC], const f32x4* __restrict__ xg,
                                               int base, int rsub, int a, int c) {
#pragma unroll
    for (int p = 0; p < LPC; ++p)
        v[p] = xg[(size_t)(base + p * 4 + rsub) * RPF + (size_t)c * 16 + a];
}

__device__ __forceinline__ void stage_chunk(const f32x4 (&v)[LPC], float* xs, int rsub, int a) {
#pragma unroll
    for (int p = 0; p < LPC; ++p) {
        const int r = p * 4 + rsub;
        ((f32x4*)&xs[r * PAD])[a] = v[p];          // one ds_write_b128, 16B-aligned
    }
}

__device__ __forceinline__ void store_chunk(const float* xs, const float* msb,
                                            f32x4* __restrict__ sg, f32x4* __restrict__ mg,
                                            int base, int rsub, int a, int c) {
#pragma unroll
    for (int p = 0; p < LPC; ++p) {
        const int r = p * 4 + rsub;
        const f32x4 sv = ((const f32x4*)&xs [r * PAD])[a];   // ds_read_b128
        const f32x4 mv = ((const f32x4*)&msb[r * PAD])[a];   // ds_read_b128
        const size_t gi = (size_t)(base + r) * RPF + (size_t)c * 16 + a;
        sg[gi] = sv;                                          // plain store, through L2
        mg[gi] = mv;
    }
}

__global__ __launch_bounds__(BLOCK, 1) void lif_scan_kernel(
    const float* __restrict__ x,
    const float* __restrict__ beta_p,
    const float* __restrict__ thr_p,
    const float* __restrict__ init_u,
    float* __restrict__ out)
{
#pragma clang fp contract(off)
    __shared__ float xs [ROWS * PAD];   // x tile in, spike tile out (reused in place)
    __shared__ float msb[ROWS * PAD];   // mems tile

    const int t    = threadIdx.x;       // 0..63
    const int base = blockIdx.x * ROWS;
    const int rsub = t >> 4;            // 0..3: row-within-pass for I/O role
    const int a    = t & 15;            // 0..15: float4 index within 256B chunk

    const float thr  = thr_p[0];
    const float beta = (float)(1.0 / (1.0 + exp(-(double)beta_p[0])));
    float mem = 0.0f;
    if (t < ROWS) mem = __fmul_rn(init_u[base + t], thr);   // mem0, row base+t

    const f32x4* __restrict__ xg = (const f32x4*)x;
    f32x4* __restrict__ sg = (f32x4*)out;
    f32x4* __restrict__ mg = (f32x4*)(out + (size_t)N_BATCH * T_STEPS);

    f32x4 va[LPC], vb[LPC];
    prefetch_chunk(va, xg, base, rsub, a, 0);
    prefetch_chunk(vb, xg, base, rsub, a, 1);

    // compute: lane t (<ROWS) scans row base+t over TILE steps, 4 at a time:
    // 1 ds_read_b128 + 4 scan steps in regs + 2 ds_write_b128 per quad.
    auto compute_chunk = [&]() {
#pragma clang fp contract(off)
        if (t < ROWS) {
            f32x4* xrow = (f32x4*)&xs [t * PAD];
            f32x4* mrow = (f32x4*)&msb[t * PAD];
#pragma unroll
            for (int q = 0; q < TILE / 4; ++q) {
                const f32x4 xv4 = xrow[q];
                f32x4 sv, mv;
#pragma unroll
                for (int j = 0; j < 4; ++j) {
                    const float mem_in  = mem;
                    const float mem_upd = __fadd_rn(__fmul_rn(beta, mem), xv4[j]);
                    const float surplus = __fsub_rn(mem_upd, thr);
                    const float hard    = (surplus >= 0.0f) ? 1.0f : 0.0f;
                    sv[j] = hard;       // spike forward value == hard
                    mv[j] = mem_in;     // mems logs memory BEFORE the step
                    mem = __fsub_rn(mem_upd, __fmul_rn(hard, thr));
                }
                xrow[q] = sv;           // overwrites consumed x quad (in place)
                mrow[q] = mv;
            }
        }
    };

    for (int c = 0; c < NCH; c += 2) {
        // ---- even chunk: data in va ----
        stage_chunk(va, xs, rsub, a);                          // waits on va loads only
        if (c + 2 < NCH) prefetch_chunk(va, xg, base, rsub, a, c + 2);
        WAVE_FENCE();   // stage xs writes  || compute xs reads
        compute_chunk();
        WAVE_FENCE();   // compute xs/msb writes || store reads
        store_chunk(xs, msb, sg, mg, base, rsub, a, c);
        WAVE_FENCE();   // store reads || next stage/compute writes

        // ---- odd chunk: data in vb ----
        stage_chunk(vb, xs, rsub, a);
        if (c + 3 < NCH) prefetch_chunk(vb, xg, base, rsub, a, c + 3);
        WAVE_FENCE();
        compute_chunk();
        WAVE_FENCE();
        store_chunk(xs, msb, sg, mg, base, rsub, a, c + 1);
        WAVE_FENCE();
    }
}

extern "C" void kernel_launch(void* const* d_in, const int* in_sizes, int n_in,
                              void* d_out, int out_size, void* d_ws, size_t ws_size,
                              hipStream_t stream) {
    const float* x      = (const float*)d_in[0];
    const float* beta_  = (const float*)d_in[1];
    const float* thresh = (const float*)d_in[2];
    const float* init_u = (const float*)d_in[3];
    float* out = (float*)d_out;

    dim3 block(BLOCK);
    dim3 grid(N_BATCH / ROWS);   // 4096 blocks -> 16 per CU (4 waves/SIMD)
    lif_scan_kernel<<<grid, block, 0, stream>>>(x, beta_, thresh, init_u, out);
}